// Round 8
// baseline (184.319 us; speedup 1.0000x reference)
//
#include <hip/hip_runtime.h>
#include <math.h>

// DCT2net, R13: R12 + occupancy fill (NSEG 20 = 5 blocks/CU at VGPR-96 limit)
// + pnz 4-way accumulation + masked Hg store.
//
// R12 post-mortem: bank conflicts 454K->0 but dur flat (~122us) => those waits
// weren't binding. k3 single-wave diagnostic: gap (~54us) unchanged across 3
// different k3 structures => gap = harness aux dispatches (restore/memset) +
// inter-dispatch time. k3 is done; k2 is the only controllable cost.
//
// R13 theory: steady step ~348 VALU slots (~700cyc issue), busy 78% => fill
// idle with waves: grid was 4 blocks/CU, VGPR 96 allows 5 waves/SIMD.
//  - NSEG 16->20 (SEGH 25; 19*25+13=488): 1280 blocks = 20 waves/CU.
//  - pnzr serial 13-FMA chain -> 4 accumulators (manual reassociation).
//  - Hg store masked jj<13: planes 13..15 were 6MB/iter of dead writes.
//
// ws: Hg = 2*488*16*512 f32 (31.98 MB), Wg = 2*512*512 f32 (2 MB).

#define P13    13
#define IMGW   512
#define OUTW   488
#define SEGH   25      // 19*25 + 13 = 488
#define NSEG   20
#define HCOLS  512
#define HPITCH 16

struct C1mat { float v[P13 * P13]; };

// ---- compile-time DCT tables ----
constexpr double kPI = 3.14159265358979323846264338327950288;

constexpr double ccos_pm_pi(double th) {   // Taylor, |th| <= pi
    double term = 1.0, s = 1.0;
    const double th2 = th * th;
    for (int n = 1; n <= 25; ++n) {
        term *= -th2 / (double)((2 * n - 1) * (2 * n));
        s += term;
    }
    return s;
}
constexpr double csqrt(double v) {
    double x = (v > 1.0) ? v : 1.0;
    for (int i = 0; i < 64; ++i) x = 0.5 * (x + v / x);
    return x;
}
constexpr C1mat make_c1() {
    C1mat m{};
    const double s213 = csqrt(2.0 / 13.0);
    const double is2  = 1.0 / csqrt(2.0);
    for (int x = 0; x < P13; ++x)
        for (int k = 0; k < P13; ++k) {
            int mm = ((2 * x + 1) * k) % 52;
            double th = (mm <= 26) ? (mm * kPI / 26.0) : ((mm - 52) * kPI / 26.0);
            double Ci = (k == 0) ? is2 : 1.0;
            m.v[x * P13 + k] = (float)(s213 * Ci * ccos_pm_pi(th));
        }
    return m;
}
__device__ constexpr C1mat c1c = make_c1();

// c1[r][c] = sgn*A[idx]; A[q] = s213*cos(q*pi/26) (q=0..12), A[13] = s213/sqrt2.
// b[q] = 2*cos((q+1)*pi/13), q=0..5 (sliding-DCT recurrence constants).
struct CTab { int idx[P13][P13]; bool neg[P13][P13]; float a[14]; float b[6]; };
constexpr CTab make_ctab() {
    CTab t{};
    const double s213 = csqrt(2.0 / 13.0);
    for (int q = 0; q <= 12; ++q) t.a[q] = (float)(s213 * ccos_pm_pi(q * kPI / 26.0));
    t.a[13] = (float)(s213 / csqrt(2.0));
    for (int q = 0; q < 6; ++q) t.b[q] = (float)(2.0 * ccos_pm_pi((q + 1) * kPI / 13.0));
    for (int r = 0; r < P13; ++r)
        for (int c = 0; c < P13; ++c) {
            if (c == 0) { t.idx[r][c] = 13; t.neg[r][c] = false; continue; }
            int m = ((2 * r + 1) * c) % 52;
            int q; bool n;
            if (m <= 13)      { q = m;      n = false; }
            else if (m <= 26) { q = 26 - m; n = true;  }
            else if (m <= 39) { q = m - 26; n = true;  }
            else              { q = 52 - m; n = false; }
            t.idx[r][c] = q; t.neg[r][c] = n;
        }
    return t;
}
constexpr CTab ctab = make_ctab();

#define KC(r, c) (ctab.neg[(r)][(c)] ? -As[ctab.idx[(r)][(c)]] : As[ctab.idx[(r)][(c)]])

struct FalseT { static constexpr bool value = false; };
struct TrueT  { static constexpr bool value = true; };

// rotate-reduce add within each 16-lane DPP row: N in {1,2,4,8}
#define ROR16_ADD(v, N)                                                        \
    v += __int_as_float(__builtin_amdgcn_mov_dpp(__float_as_int(v),            \
                                                 0x120 + (N), 0xF, 0xF, true))

// weighted vertical inverse fold (scaled domain)
__device__ __forceinline__ void fold_vert(const float (&tn)[P13], const float (&As)[14],
                                          float w1, float (&H)[P13])
{
#pragma unroll
    for (int dx = 0; dx < 6; ++dx) {
        float E = KC(dx, 0) * tn[0];
#pragma unroll
        for (int i = 2; i < P13; i += 2) E = fmaf(KC(dx, i), tn[i], E);
        float O = KC(dx, 1) * tn[1];
#pragma unroll
        for (int i = 3; i < P13; i += 2) O = fmaf(KC(dx, i), tn[i], O);
        H[dx]      = fmaf(w1, E + O, H[dx]);
        H[12 - dx] = fmaf(w1, E - O, H[12 - dx]);
    }
    float z6 = KC(6, 0) * tn[0];
#pragma unroll
    for (int i = 2; i < P13; i += 2) z6 = fmaf(KC(6, i), tn[i], z6);
    H[6] = fmaf(w1, z6, H[6]);
}

__global__ __launch_bounds__(256) void dct2net_k2(
    const float* __restrict__ xg, const float* __restrict__ sigmag,
    float* __restrict__ Hg, float* __restrict__ Wg)
{
    __shared__ float c1lds[169];
    __shared__ float xlds[4][4][16];       // stride 16: 2 lanes/bank = free
    const int tid = threadIdx.x;
    if (tid < 169) c1lds[tid] = c1c.v[tid];
    __syncthreads();                       // once, for the c1 table only

    const int lane = tid & 63;
    const int wv   = tid >> 6;
    const int g    = lane >> 4;            // col group 0..3
    const int jj   = lane & 15;            // kj (0..12 used)
    const int img  = blockIdx.z;
    const int hs   = blockIdx.y * SEGH;
    const int segrows = (OUTW - hs < SEGH) ? (OUTW - hs) : SEGH;
    const int cbw  = blockIdx.x * 16 + wv * 4;
    const int col  = cbw + g;

    const float inv3s = 1.0f / (3.0f * sigmag[0]);
    const float* xin  = xg + (size_t)img * IMGW * IMGW;

    // SGPR constant pools
    float As[14], Bs[6];
#pragma unroll
    for (int q = 0; q < 14; ++q) As[q] = ctab.a[q];
#pragma unroll
    for (int q = 0; q < 6; ++q) Bs[q] = ctab.b[q];
#pragma unroll
    for (int q = 0; q < 14; ++q) asm("" : "+s"(As[q]));
#pragma unroll
    for (int q = 0; q < 6; ++q) asm("" : "+s"(Bs[q]));

    // per-lane window coefficients over staged positions p=0..15:
    // c1x[p] = c1[p-g][jj] * inv3s inside the window, 0 outside / idle lanes
    float c1x[16];
#pragma unroll
    for (int p = 0; p < 16; ++p) {
        int y = p - g;
        int yc = (y < 0) ? 0 : ((y > 12) ? 12 : y);
        int jc = (jj < 13) ? jj : 0;
        float v = c1lds[yc * 13 + jc];
        c1x[p] = (y >= 0 && y < 13 && jj < 13) ? v * inv3s : 0.0f;
    }

    float T0[P13], T1[P13], dr[P13], Hr[P13], wr[12], Rv[P13];
#pragma unroll
    for (int k = 0; k < P13; ++k) { T0[k]=0; T1[k]=0; dr[k]=0; Hr[k]=0; Rv[k]=0; }
#pragma unroll
    for (int k = 0; k < 12; ++k) wr[k] = 0.0f;
    float vs = 0.0f, Rprev = 0.0f;

    int xcol = cbw + (lane & 15); xcol = (xcol < IMGW - 1) ? xcol : (IMGW - 1);
    const float* xlast = xin + (size_t)(IMGW - 1) * IMGW;

    // ---- pre-roll: stage row hs, read its window into xq, xvA <- row hs+1 ----
    float xq[16];
    float xvA, xvB;
    {
        const float* r0 = xin + (size_t)hs * IMGW;
        xlds[wv][g][jj] = r0[xcol];
        float4 q0 = *(const float4*)&xlds[wv][g][0];
        float4 q1 = *(const float4*)&xlds[wv][g][4];
        float4 q2 = *(const float4*)&xlds[wv][g][8];
        float4 q3 = *(const float4*)&xlds[wv][g][12];
        xq[0]=q0.x; xq[1]=q0.y; xq[2]=q0.z; xq[3]=q0.w;
        xq[4]=q1.x; xq[5]=q1.y; xq[6]=q1.z; xq[7]=q1.w;
        xq[8]=q2.x; xq[9]=q2.y; xq[10]=q2.z; xq[11]=q2.w;
        xq[12]=q3.x; xq[13]=q3.y; xq[14]=q3.z; xq[15]=q3.w;
        const float* r1 = xin + (size_t)(hs + 1) * IMGW;
        xvA = r1[xcol];
    }
    const float* xp = xin + (size_t)(hs + 2) * IMGW;

    float* Hp = Hg + ((size_t)img * OUTW + hs) * HPITCH * HCOLS;
    float* Wp = Wg + ((size_t)img * IMGW + hs) * IMGW;
    const int voH = jj * HCOLS + col;      // jj-plane layout
    const int voW = col;

    // hDCT of the CURRENT row from the pipelined window registers
    auto hdct = [&]() -> float {
        float a0 = c1x[0] * xq[0], a1 = c1x[1] * xq[1];
#pragma unroll
        for (int p = 2; p < 16; p += 2) a0 = fmaf(c1x[p], xq[p], a0);
#pragma unroll
        for (int p = 3; p < 16; p += 2) a1 = fmaf(c1x[p], xq[p], a1);
        return a0 + a1;
    };
    // stage NEXT row (xvW) to LDS, read its window into xq (latency hidden
    // under this step's math + next step's front), prefetch row after.
    auto advance = [&](float xvW, float& xvL) {
        xlds[wv][g][jj] = xvW;
        float4 q0 = *(const float4*)&xlds[wv][g][0];
        float4 q1 = *(const float4*)&xlds[wv][g][4];
        float4 q2 = *(const float4*)&xlds[wv][g][8];
        float4 q3 = *(const float4*)&xlds[wv][g][12];
        xq[0]=q0.x; xq[1]=q0.y; xq[2]=q0.z; xq[3]=q0.w;
        xq[4]=q1.x; xq[5]=q1.y; xq[6]=q1.z; xq[7]=q1.w;
        xq[8]=q2.x; xq[9]=q2.y; xq[10]=q2.z; xq[11]=q2.w;
        xq[12]=q3.x; xq[13]=q3.y; xq[14]=q3.z; xq[15]=q3.w;
        const float* xr = (xp < xlast) ? xp : xlast;
        xvL = xr[xcol]; xp += IMGW;
    };
    auto pushRv = [&](float Rn) {
#pragma unroll
        for (int q = 0; q < P13 - 1; ++q) Rv[q] = Rv[q + 1];
        Rv[P13 - 1] = Rn;
    };
    auto pushd = [&](float Rn) {
        float dn = Rn - Rprev; Rprev = Rn;
#pragma unroll
        for (int q = 0; q < P13 - 1; ++q) dr[q] = dr[q + 1];
        dr[P13 - 1] = dn;
    };
    auto matvec = [&](float (&T)[P13]) {   // bootstrap only
        float Se[6], So[6];
#pragma unroll
        for (int k = 0; k < 6; ++k) { Se[k] = Rv[k] + Rv[12 - k]; So[k] = Rv[k] - Rv[12 - k]; }
#pragma unroll
        for (int i = 0; i < P13; ++i) {
            float t;
            if ((i & 1) == 0) {
                t = KC(6, i) * Rv[6];
#pragma unroll
                for (int k = 0; k < 6; ++k) t = fmaf(KC(k, i), Se[k], t);
            } else {
                t = KC(0, i) * So[0];
#pragma unroll
                for (int k = 1; k < 6; ++k) t = fmaf(KC(k, i), So[k], t);
            }
            T[i] = t;
        }
    };
    // shrink + butterfly + fold + (runtime) retire. T pre-scaled (u = t).
    auto sf = [&](const float (&T)[P13], bool rt) {
        float tn[P13];
        float pz0 = 0.0f, pz1 = 0.0f, pz2 = 0.0f, pz3 = 0.0f;  // 4-way accum
#pragma unroll
        for (int i = 0; i < P13; ++i) {
            float p2 = fminf(T[i] * T[i], 1.69f);
            float p4 = p2 * p2, p8 = p4 * p4, p16 = p8 * p8, p32 = p16 * p16, p64 = p32 * p32;
            float r  = __builtin_amdgcn_rcpf(p64 + 1.0f);
            if ((i & 3) == 0) pz0 += r;
            else if ((i & 3) == 1) pz1 += r;
            else if ((i & 3) == 2) pz2 += r;
            else pz3 += r;
            tn[i] = fmaf(-T[i], r, T[i]);
        }
        float pnz = 13.0f - ((pz0 + pz1) + (pz2 + pz3));  // idle lanes: exactly 0
        ROR16_ADD(pnz, 1); ROR16_ADD(pnz, 2); ROR16_ADD(pnz, 4); ROR16_ADD(pnz, 8);
        const float w = __builtin_amdgcn_rcpf(1.0f + pnz);
        vs += w;
        fold_vert(tn, As, w, Hr);
        if (rt) {                           // uniform branch
            if (jj < 13) Hp[voH] = Hr[0];   // planes 13..15 never read: skip
            Hp += HPITCH * HCOLS;
            if (jj == 0) Wp[voW] = vs;
            Wp += IMGW;
            vs -= wr[0];
        }
#pragma unroll
        for (int q = 0; q < 11; ++q) wr[q] = wr[q + 1];
        wr[11] = w;
#pragma unroll
        for (int q = 0; q < P13 - 1; ++q) Hr[q] = Hr[q + 1];
        Hr[P13 - 1] = 0.0f;
    };
    auto recur = [&](auto INTOT0, float& xvW, float& xvL, bool rt) {
        float Rn = hdct();
        advance(xvW, xvL);
        float dn = Rn - Rprev; Rprev = Rn;
        float dl = dr[0];
#pragma unroll
        for (int q = 0; q < P13 - 1; ++q) dr[q] = dr[q + 1];
        dr[P13 - 1] = dn;
        float Pe = dn - dl, Po = dn + dl;
#pragma unroll
        for (int i = 0; i < P13; ++i) {
            float tp2 = decltype(INTOT0)::value ? T0[i] : T1[i];
            float tp1 = decltype(INTOT0)::value ? T1[i] : T0[i];
            float c2 = (i == 0) ? 2.0f : ((i <= 6) ? Bs[i - 1] : -Bs[12 - i]);
            float t = fmaf(c2, tp1, -tp2);
            float kc = (i == 0) ? As[13] : As[i];
            t = (i & 1) ? fmaf(-kc, Po, t) : fmaf(kc, Pe, t);
            if constexpr (decltype(INTOT0)::value) T0[i] = t; else T1[i] = t;
        }
        if constexpr (decltype(INTOT0)::value) sf(T0, rt); else sf(T1, rt);
    };

    // ---- ramp1: k=0..11 (even k -> xvA staged, odd k -> xvB) ----
    { float Rn = hdct(); advance(xvA, xvB); Rprev = Rn; pushRv(Rn); }
    { float Rn = hdct(); advance(xvB, xvA); pushd(Rn); pushRv(Rn); }
#pragma unroll 1
    for (int k = 2; k < 12; k += 2) {
        float Rn = hdct(); advance(xvA, xvB); pushd(Rn); pushRv(Rn);
        float Rm = hdct(); advance(xvB, xvA); pushd(Rm); pushRv(Rm);
    }
    // ---- bootstrap: direct matvecs at k=12,13 ----
    { float Rn = hdct(); advance(xvA, xvB); pushd(Rn); pushRv(Rn); matvec(T0); sf(T0, false); }
    { float Rn = hdct(); advance(xvB, xvA); pushd(Rn); pushRv(Rn); matvec(T1); sf(T1, false); }
    // ---- steady: recurrence pairs; retire from steady-step 10 on ----
    {
        int ks = 0; const int S = 10 + segrows;
#pragma unroll 1
        while (ks + 2 <= S) {
            recur(TrueT{},  xvA, xvB, ks     >= 10);
            recur(FalseT{}, xvB, xvA, ks + 1 >= 10);
            ks += 2;
        }
        if (ks < S) recur(TrueT{}, xvA, xvB, ks >= 10);
    }
}

__global__ __launch_bounds__(64) void dct2net_k3(
    const float* __restrict__ Hg, const float* __restrict__ Wg,
    const float* __restrict__ sigmag, float* __restrict__ outg)
{
    __shared__ float U[76][15];      // stride 15: diag read 2-way alias (free)
    __shared__ float vw[80];
    const int lane = threadIdx.x;    // single wave per block
    const int img  = blockIdx.z;
    const int a    = blockIdx.y;     // out row 0..487
    const int cb   = blockIdx.x * 64;

    const float t3s = 3.0f * sigmag[0];     // undo k2's scaled domain

    float As[14];
#pragma unroll
    for (int q = 0; q < 14; ++q) As[q] = ctab.a[q];
#pragma unroll
    for (int q = 0; q < 14; ++q) asm("" : "+s"(As[q]));

    // ---- coalesced loads from jj-plane Hg (main + halo issued up front) ----
    int c = cb + lane; c = (c < 499) ? c : 499;
    const float* hb = Hg + ((size_t)img * OUTW + a) * HPITCH * HCOLS + c;
    float hv[P13];
#pragma unroll
    for (int j = 0; j < P13; ++j) hv[j] = hb[j * HCOLS];
    float wm = Wg[((size_t)img * IMGW + a) * IMGW + c];

    const bool halo = (lane < 12);
    float sv[P13]; float ws = 0.0f;
#pragma unroll
    for (int j = 0; j < P13; ++j) sv[j] = 0.0f;
    if (halo) {
        int c2 = cb + 64 + lane; c2 = (c2 < 499) ? c2 : 499;
        const float* hq = Hg + ((size_t)img * OUTW + a) * HPITCH * HCOLS + c2;
#pragma unroll
        for (int j = 0; j < P13; ++j) sv[j] = hq[j * HCOLS];
        ws = Wg[((size_t)img * IMGW + a) * IMGW + c2];
    }

    // U build with row symmetry: c1[12-dy][j] = (-1)^j c1[dy][j]
    auto buildU = [&](const float (&h)[P13], int uli) {
#pragma unroll
        for (int dy = 0; dy < 6; ++dy) {
            float e = KC(dy, 0) * h[0];
#pragma unroll
            for (int j = 2; j < P13; j += 2) e = fmaf(KC(dy, j), h[j], e);
            float o = KC(dy, 1) * h[1];
#pragma unroll
            for (int j = 3; j < P13; j += 2) o = fmaf(KC(dy, j), h[j], o);
            U[uli][dy]      = e + o;
            U[uli][12 - dy] = e - o;
        }
        float gsum = ((h[4] - h[2]) + (h[8] - h[6])) + (h[12] - h[10]);
        U[uli][6] = fmaf(As[0], gsum, As[13] * h[0]);
    };

    buildU(hv, lane);
    vw[lane] = wm;
    if (halo) {
        buildU(sv, 64 + lane);
        vw[64 + lane] = ws;
    }
    // single wave: LDS write->read in program order, no barrier

    float num = 0.0f;
#pragma unroll
    for (int dy = 0; dy < P13; ++dy) num += U[lane + 12 - dy][dy];
    float den = 0.0f;
#pragma unroll
    for (int d = 0; d < P13; ++d) den += vw[lane + d];
    const int ow = cb + lane;
    if (ow < OUTW)
        outg[((size_t)img * OUTW + a) * OUTW + ow] =
            num * t3s * __builtin_amdgcn_rcpf(den);
}

extern "C" void kernel_launch(void* const* d_in, const int* in_sizes, int n_in,
                              void* d_out, int out_size, void* d_ws, size_t ws_size,
                              hipStream_t stream)
{
    const float* x     = (const float*)d_in[0];
    const float* sigma = (const float*)d_in[1];
    float* out = (float*)d_out;

    // ws: Hg (2*488*16*512 f32 = 31.98 MB) then Wg (2*512*512 f32 = 2 MB)
    float* Hg = (float*)d_ws;
    float* Wg = Hg + (size_t)2 * OUTW * HPITCH * HCOLS;

    dct2net_k2<<<dim3(32, NSEG, 2), 256, 0, stream>>>(x, sigma, Hg, Wg);
    dct2net_k3<<<dim3(8, 488, 2), 64, 0, stream>>>(Hg, Wg, sigma, out);
}

// Round 10
// 175.512 us; speedup vs baseline: 1.0502x; 1.0502x over previous
//
#include <hip/hip_runtime.h>
#include <math.h>

// DCT2net, R15: R14 with the shift2 bug fixed (dropped accumulator).
//
// R14 post-mortem: absmax 8.59e-2 = output/13 -> one fold contribution lost
// per 2 rows. Phase B folds logical 12 into phys 0; shift2 must carry old
// phys 0 into new phys 11 (was zeroed). One-line fix; everything else kept
// so R14's timing experiment (LDS delay lines + 2-phase Hr rotation,
// ~-25 movs/step) actually measures.
//
// Structure (R12 base): per lane-group of 16, one patch column; LDS-staged
// 16-wide x window (2 lanes/bank writes, b128 broadcast reads), software-
// pipelined 2-row-ahead; sliding-DCT vertical recurrence (2 FMA/coeff);
// scaled domain (inv3s folded into hDCT coeffs, k3 multiplies back);
// DPP ROR16 butterfly for pnz; dr/wr as LDS delay lines; masked jj<13 Hg
// store; jj-plane Hg layout; single-wave k3.
//
// ws: Hg = 2*488*16*512 f32 (31.98 MB), Wg = 2*512*512 f32 (2 MB).

#define P13    13
#define IMGW   512
#define OUTW   488
#define SEGH   31      // 15*31 + 23 = 488
#define NSEG   16
#define HCOLS  512
#define HPITCH 16

struct C1mat { float v[P13 * P13]; };

// ---- compile-time DCT tables ----
constexpr double kPI = 3.14159265358979323846264338327950288;

constexpr double ccos_pm_pi(double th) {   // Taylor, |th| <= pi
    double term = 1.0, s = 1.0;
    const double th2 = th * th;
    for (int n = 1; n <= 25; ++n) {
        term *= -th2 / (double)((2 * n - 1) * (2 * n));
        s += term;
    }
    return s;
}
constexpr double csqrt(double v) {
    double x = (v > 1.0) ? v : 1.0;
    for (int i = 0; i < 64; ++i) x = 0.5 * (x + v / x);
    return x;
}
constexpr C1mat make_c1() {
    C1mat m{};
    const double s213 = csqrt(2.0 / 13.0);
    const double is2  = 1.0 / csqrt(2.0);
    for (int x = 0; x < P13; ++x)
        for (int k = 0; k < P13; ++k) {
            int mm = ((2 * x + 1) * k) % 52;
            double th = (mm <= 26) ? (mm * kPI / 26.0) : ((mm - 52) * kPI / 26.0);
            double Ci = (k == 0) ? is2 : 1.0;
            m.v[x * P13 + k] = (float)(s213 * Ci * ccos_pm_pi(th));
        }
    return m;
}
__device__ constexpr C1mat c1c = make_c1();

// c1[r][c] = sgn*A[idx]; A[q] = s213*cos(q*pi/26) (q=0..12), A[13] = s213/sqrt2.
// b[q] = 2*cos((q+1)*pi/13) (sliding-DCT recurrence constants).
struct CTab { int idx[P13][P13]; bool neg[P13][P13]; float a[14]; float b[6]; };
constexpr CTab make_ctab() {
    CTab t{};
    const double s213 = csqrt(2.0 / 13.0);
    for (int q = 0; q <= 12; ++q) t.a[q] = (float)(s213 * ccos_pm_pi(q * kPI / 26.0));
    t.a[13] = (float)(s213 / csqrt(2.0));
    for (int q = 0; q < 6; ++q) t.b[q] = (float)(2.0 * ccos_pm_pi((q + 1) * kPI / 13.0));
    for (int r = 0; r < P13; ++r)
        for (int c = 0; c < P13; ++c) {
            if (c == 0) { t.idx[r][c] = 13; t.neg[r][c] = false; continue; }
            int m = ((2 * r + 1) * c) % 52;
            int q; bool n;
            if (m <= 13)      { q = m;      n = false; }
            else if (m <= 26) { q = 26 - m; n = true;  }
            else if (m <= 39) { q = m - 26; n = true;  }
            else              { q = 52 - m; n = false; }
            t.idx[r][c] = q; t.neg[r][c] = n;
        }
    return t;
}
constexpr CTab ctab = make_ctab();

#define KC(r, c) (ctab.neg[(r)][(c)] ? -As[ctab.idx[(r)][(c)]] : As[ctab.idx[(r)][(c)]])

struct FalseT { static constexpr bool value = false; };
struct TrueT  { static constexpr bool value = true; };

// rotate-reduce add within each 16-lane DPP row: N in {1,2,4,8}
#define ROR16_ADD(v, N)                                                        \
    v += __int_as_float(__builtin_amdgcn_mov_dpp(__float_as_int(v),            \
                                                 0x120 + (N), 0xF, 0xF, true))

// weighted vertical inverse fold, ring rotation R (logical d -> phys (d+R)%13)
template<int R>
__device__ __forceinline__ void fold_vert(const float (&tn)[P13], const float (&As)[14],
                                          float w1, float (&H)[P13])
{
#pragma unroll
    for (int dx = 0; dx < 6; ++dx) {
        float E = KC(dx, 0) * tn[0];
#pragma unroll
        for (int i = 2; i < P13; i += 2) E = fmaf(KC(dx, i), tn[i], E);
        float O = KC(dx, 1) * tn[1];
#pragma unroll
        for (int i = 3; i < P13; i += 2) O = fmaf(KC(dx, i), tn[i], O);
        H[(dx + R) % P13]      = fmaf(w1, E + O, H[(dx + R) % P13]);
        H[(12 - dx + R) % P13] = fmaf(w1, E - O, H[(12 - dx + R) % P13]);
    }
    float z6 = KC(6, 0) * tn[0];
#pragma unroll
    for (int i = 2; i < P13; i += 2) z6 = fmaf(KC(6, i), tn[i], z6);
    H[(6 + R) % P13] = fmaf(w1, z6, H[(6 + R) % P13]);
}

__global__ __launch_bounds__(256) void dct2net_k2(
    const float* __restrict__ xg, const float* __restrict__ sigmag,
    float* __restrict__ Hg, float* __restrict__ Wg)
{
    __shared__ float c1lds[169];
    __shared__ float xlds[4][4][16];       // stride 16: 2 lanes/bank = free
    __shared__ float dline[13][256];       // 13-step delay line for d
    __shared__ float wline[12][256];       // 12-step delay line for w
    const int tid = threadIdx.x;
    if (tid < 169) c1lds[tid] = c1c.v[tid];
    __syncthreads();                       // once, for the c1 table only

    const int lane = tid & 63;
    const int wv   = tid >> 6;
    const int g    = lane >> 4;            // col group 0..3
    const int jj   = lane & 15;            // kj (0..12 used)
    const int img  = blockIdx.z;
    const int hs   = blockIdx.y * SEGH;
    const int segrows = (OUTW - hs < SEGH) ? (OUTW - hs) : SEGH;
    const int cbw  = blockIdx.x * 16 + wv * 4;
    const int col  = cbw + g;

    const float inv3s = 1.0f / (3.0f * sigmag[0]);
    const float* xin  = xg + (size_t)img * IMGW * IMGW;

    // SGPR constant pools
    float As[14], Bs[6];
#pragma unroll
    for (int q = 0; q < 14; ++q) As[q] = ctab.a[q];
#pragma unroll
    for (int q = 0; q < 6; ++q) Bs[q] = ctab.b[q];
#pragma unroll
    for (int q = 0; q < 14; ++q) asm("" : "+s"(As[q]));
#pragma unroll
    for (int q = 0; q < 6; ++q) asm("" : "+s"(Bs[q]));

    // per-lane window coefficients over staged positions p=0..15
    float c1x[16];
#pragma unroll
    for (int p = 0; p < 16; ++p) {
        int y = p - g;
        int yc = (y < 0) ? 0 : ((y > 12) ? 12 : y);
        int jc = (jj < 13) ? jj : 0;
        float v = c1lds[yc * 13 + jc];
        c1x[p] = (y >= 0 && y < 13 && jj < 13) ? v * inv3s : 0.0f;
    }

    float T0[P13], T1[P13], Hr[P13], Rv[P13];
#pragma unroll
    for (int k = 0; k < P13; ++k) { T0[k]=0; T1[k]=0; Hr[k]=0; Rv[k]=0; }
    float vs = 0.0f, Rprev = 0.0f;
    float dl_pre = 0.0f, wold_pre = 0.0f;
    int dslot = 0, wslot = 0;

    int xcol = cbw + (lane & 15); xcol = (xcol < IMGW - 1) ? xcol : (IMGW - 1);
    const float* xlast = xin + (size_t)(IMGW - 1) * IMGW;

    // ---- pre-roll: stage row hs, read window into xq, xvA <- row hs+1 ----
    float xq[16];
    float xvA, xvB;
    {
        const float* r0 = xin + (size_t)hs * IMGW;
        xlds[wv][g][jj] = r0[xcol];
        float4 q0 = *(const float4*)&xlds[wv][g][0];
        float4 q1 = *(const float4*)&xlds[wv][g][4];
        float4 q2 = *(const float4*)&xlds[wv][g][8];
        float4 q3 = *(const float4*)&xlds[wv][g][12];
        xq[0]=q0.x; xq[1]=q0.y; xq[2]=q0.z; xq[3]=q0.w;
        xq[4]=q1.x; xq[5]=q1.y; xq[6]=q1.z; xq[7]=q1.w;
        xq[8]=q2.x; xq[9]=q2.y; xq[10]=q2.z; xq[11]=q2.w;
        xq[12]=q3.x; xq[13]=q3.y; xq[14]=q3.z; xq[15]=q3.w;
        const float* r1 = xin + (size_t)(hs + 1) * IMGW;
        xvA = r1[xcol];
    }
    const float* xp = xin + (size_t)(hs + 2) * IMGW;

    float* Hp = Hg + ((size_t)img * OUTW + hs) * HPITCH * HCOLS;
    float* Wp = Wg + ((size_t)img * IMGW + hs) * IMGW;
    const int voH = jj * HCOLS + col;      // jj-plane layout
    const int voW = col;

    auto hdct = [&]() -> float {
        float a0 = c1x[0] * xq[0], a1 = c1x[1] * xq[1];
#pragma unroll
        for (int p = 2; p < 16; p += 2) a0 = fmaf(c1x[p], xq[p], a0);
#pragma unroll
        for (int p = 3; p < 16; p += 2) a1 = fmaf(c1x[p], xq[p], a1);
        return a0 + a1;
    };
    auto advance = [&](float xvW, float& xvL) {
        xlds[wv][g][jj] = xvW;
        float4 q0 = *(const float4*)&xlds[wv][g][0];
        float4 q1 = *(const float4*)&xlds[wv][g][4];
        float4 q2 = *(const float4*)&xlds[wv][g][8];
        float4 q3 = *(const float4*)&xlds[wv][g][12];
        xq[0]=q0.x; xq[1]=q0.y; xq[2]=q0.z; xq[3]=q0.w;
        xq[4]=q1.x; xq[5]=q1.y; xq[6]=q1.z; xq[7]=q1.w;
        xq[8]=q2.x; xq[9]=q2.y; xq[10]=q2.z; xq[11]=q2.w;
        xq[12]=q3.x; xq[13]=q3.y; xq[14]=q3.z; xq[15]=q3.w;
        const float* xr = (xp < xlast) ? xp : xlast;
        xvL = xr[xcol]; xp += IMGW;
    };
    // d delay line: returns d from 13 steps ago (prefetched), records dn
    auto dring = [&](float dn) -> float {
        float dl = dl_pre;
        dline[dslot][tid] = dn;
        const int dn1 = (dslot == 12) ? 0 : dslot + 1;
        dl_pre = dline[dn1][tid];          // prefetch for NEXT step (d(m-12))
        dslot = dn1;
        return dl;
    };
    auto pushRv = [&](float Rn) {
#pragma unroll
        for (int q = 0; q < P13 - 1; ++q) Rv[q] = Rv[q + 1];
        Rv[P13 - 1] = Rn;
    };
    auto matvec = [&](float (&T)[P13]) {   // bootstrap only
        float Se[6], So[6];
#pragma unroll
        for (int k = 0; k < 6; ++k) { Se[k] = Rv[k] + Rv[12 - k]; So[k] = Rv[k] - Rv[12 - k]; }
#pragma unroll
        for (int i = 0; i < P13; ++i) {
            float t;
            if ((i & 1) == 0) {
                t = KC(6, i) * Rv[6];
#pragma unroll
                for (int k = 0; k < 6; ++k) t = fmaf(KC(k, i), Se[k], t);
            } else {
                t = KC(0, i) * So[0];
#pragma unroll
                for (int k = 1; k < 6; ++k) t = fmaf(KC(k, i), So[k], t);
            }
            T[i] = t;
        }
    };
    // shrink + butterfly + fold + (runtime) retire at ring phase PH (0/1).
    auto sf = [&](auto PH, const float (&T)[P13], bool rt) {
        constexpr int R = decltype(PH)::value ? 1 : 0;
        float tn[P13];
        float pz0 = 0.0f, pz1 = 0.0f, pz2 = 0.0f, pz3 = 0.0f;
#pragma unroll
        for (int i = 0; i < P13; ++i) {
            float p2 = fminf(T[i] * T[i], 1.69f);
            float p4 = p2 * p2, p8 = p4 * p4, p16 = p8 * p8, p32 = p16 * p16, p64 = p32 * p32;
            float r  = __builtin_amdgcn_rcpf(p64 + 1.0f);
            if ((i & 3) == 0) pz0 += r;
            else if ((i & 3) == 1) pz1 += r;
            else if ((i & 3) == 2) pz2 += r;
            else pz3 += r;
            tn[i] = fmaf(-T[i], r, T[i]);
        }
        float pnz = 13.0f - ((pz0 + pz1) + (pz2 + pz3));
        ROR16_ADD(pnz, 1); ROR16_ADD(pnz, 2); ROR16_ADD(pnz, 4); ROR16_ADD(pnz, 8);
        const float w = __builtin_amdgcn_rcpf(1.0f + pnz);
        vs += w;
        fold_vert<R>(tn, As, w, Hr);
        // w delay line (12-deep): wold = w from 12 sf calls ago
        float wold = wold_pre;
        wline[wslot][tid] = w;
        const int wn1 = (wslot == 11) ? 0 : wslot + 1;
        wold_pre = wline[wn1][tid];
        wslot = wn1;
        if (rt) {                           // uniform branch
            if (jj < 13) Hp[voH] = Hr[R];   // planes 13..15 never read
            Hp += HPITCH * HCOLS;
            if (jj == 0) Wp[voW] = vs;
            Wp += IMGW;
            vs -= wold;
        }
        Hr[R] = 0.0f;                       // fresh accumulator slot
    };
    auto recur = [&](auto INTOT0, auto PH, float& xvW, float& xvL, bool rt) {
        float Rn = hdct();
        advance(xvW, xvL);
        float dn = Rn - Rprev; Rprev = Rn;
        float dl = dring(dn);
        float Pe = dn - dl, Po = dn + dl;
#pragma unroll
        for (int i = 0; i < P13; ++i) {
            float tp2 = decltype(INTOT0)::value ? T0[i] : T1[i];
            float tp1 = decltype(INTOT0)::value ? T1[i] : T0[i];
            float c2 = (i == 0) ? 2.0f : ((i <= 6) ? Bs[i - 1] : -Bs[12 - i]);
            float t = fmaf(c2, tp1, -tp2);
            float kc = (i == 0) ? As[13] : As[i];
            t = (i & 1) ? fmaf(-kc, Po, t) : fmaf(kc, Pe, t);
            if constexpr (decltype(INTOT0)::value) T0[i] = t; else T1[i] = t;
        }
        if constexpr (decltype(INTOT0)::value) sf(PH, T0, rt); else sf(PH, T1, rt);
    };
    // renormalize Hr after an A/B pair: new phys q <- old phys (q+2)%13.
    // old phys 0 holds logical-12's fold from phase B -> becomes new phys 11.
    // old phys 1 was retired+zeroed in phase B -> new phys 12 fresh.
    auto shift2 = [&]() {
        float h0 = Hr[0];
#pragma unroll
        for (int q = 0; q < 11; ++q) Hr[q] = Hr[q + 2];
        Hr[11] = h0; Hr[12] = 0.0f;
    };

    // ---- ramp1: k=0..11 ----
    { float Rn = hdct(); advance(xvA, xvB); Rprev = Rn; pushRv(Rn); }
    { float Rn = hdct(); advance(xvB, xvA); dring(Rn - Rprev); Rprev = Rn; pushRv(Rn); }
#pragma unroll 1
    for (int k = 2; k < 12; k += 2) {
        { float Rn = hdct(); advance(xvA, xvB); dring(Rn - Rprev); Rprev = Rn; pushRv(Rn); }
        { float Rn = hdct(); advance(xvB, xvA); dring(Rn - Rprev); Rprev = Rn; pushRv(Rn); }
    }
    // ---- bootstrap pair: direct matvecs at k=12 (phase A), k=13 (phase B) ----
    { float Rn = hdct(); advance(xvA, xvB); dring(Rn - Rprev); Rprev = Rn; pushRv(Rn);
      matvec(T0); sf(FalseT{}, T0, false); }
    { float Rn = hdct(); advance(xvB, xvA); dring(Rn - Rprev); Rprev = Rn; pushRv(Rn);
      matvec(T1); sf(TrueT{}, T1, false); }
    shift2();
    // ---- steady: recurrence pairs; retire from steady-step 10 on ----
    {
        int ks = 0; const int S = 10 + segrows;
#pragma unroll 1
        while (ks + 2 <= S) {
            recur(TrueT{},  FalseT{}, xvA, xvB, ks     >= 10);
            recur(FalseT{}, TrueT{},  xvB, xvA, ks + 1 >= 10);
            shift2();
            ks += 2;
        }
        if (ks < S) recur(TrueT{}, FalseT{}, xvA, xvB, ks >= 10);
    }
}

__global__ __launch_bounds__(64) void dct2net_k3(
    const float* __restrict__ Hg, const float* __restrict__ Wg,
    const float* __restrict__ sigmag, float* __restrict__ outg)
{
    __shared__ float U[76][15];      // stride 15: diag read 2-way alias (free)
    __shared__ float vw[80];
    const int lane = threadIdx.x;    // single wave per block
    const int img  = blockIdx.z;
    const int a    = blockIdx.y;     // out row 0..487
    const int cb   = blockIdx.x * 64;

    const float t3s = 3.0f * sigmag[0];     // undo k2's scaled domain

    float As[14];
#pragma unroll
    for (int q = 0; q < 14; ++q) As[q] = ctab.a[q];
#pragma unroll
    for (int q = 0; q < 14; ++q) asm("" : "+s"(As[q]));

    // ---- coalesced loads from jj-plane Hg (main + halo issued up front) ----
    int c = cb + lane; c = (c < 499) ? c : 499;
    const float* hb = Hg + ((size_t)img * OUTW + a) * HPITCH * HCOLS + c;
    float hv[P13];
#pragma unroll
    for (int j = 0; j < P13; ++j) hv[j] = hb[j * HCOLS];
    float wm = Wg[((size_t)img * IMGW + a) * IMGW + c];

    const bool halo = (lane < 12);
    float sv[P13]; float ws = 0.0f;
#pragma unroll
    for (int j = 0; j < P13; ++j) sv[j] = 0.0f;
    if (halo) {
        int c2 = cb + 64 + lane; c2 = (c2 < 499) ? c2 : 499;
        const float* hq = Hg + ((size_t)img * OUTW + a) * HPITCH * HCOLS + c2;
#pragma unroll
        for (int j = 0; j < P13; ++j) sv[j] = hq[j * HCOLS];
        ws = Wg[((size_t)img * IMGW + a) * IMGW + c2];
    }

    // U build with row symmetry: c1[12-dy][j] = (-1)^j c1[dy][j]
    auto buildU = [&](const float (&h)[P13], int uli) {
#pragma unroll
        for (int dy = 0; dy < 6; ++dy) {
            float e = KC(dy, 0) * h[0];
#pragma unroll
            for (int j = 2; j < P13; j += 2) e = fmaf(KC(dy, j), h[j], e);
            float o = KC(dy, 1) * h[1];
#pragma unroll
            for (int j = 3; j < P13; j += 2) o = fmaf(KC(dy, j), h[j], o);
            U[uli][dy]      = e + o;
            U[uli][12 - dy] = e - o;
        }
        float gsum = ((h[4] - h[2]) + (h[8] - h[6])) + (h[12] - h[10]);
        U[uli][6] = fmaf(As[0], gsum, As[13] * h[0]);
    };

    buildU(hv, lane);
    vw[lane] = wm;
    if (halo) {
        buildU(sv, 64 + lane);
        vw[64 + lane] = ws;
    }
    // single wave: LDS write->read in program order, no barrier

    float num = 0.0f;
#pragma unroll
    for (int dy = 0; dy < P13; ++dy) num += U[lane + 12 - dy][dy];
    float den = 0.0f;
#pragma unroll
    for (int d = 0; d < P13; ++d) den += vw[lane + d];
    const int ow = cb + lane;
    if (ow < OUTW)
        outg[((size_t)img * OUTW + a) * OUTW + ow] =
            num * t3s * __builtin_amdgcn_rcpf(den);
}

extern "C" void kernel_launch(void* const* d_in, const int* in_sizes, int n_in,
                              void* d_out, int out_size, void* d_ws, size_t ws_size,
                              hipStream_t stream)
{
    const float* x     = (const float*)d_in[0];
    const float* sigma = (const float*)d_in[1];
    float* out = (float*)d_out;

    // ws: Hg (2*488*16*512 f32 = 31.98 MB) then Wg (2*512*512 f32 = 2 MB)
    float* Hg = (float*)d_ws;
    float* Wg = Hg + (size_t)2 * OUTW * HPITCH * HCOLS;

    dct2net_k2<<<dim3(32, NSEG, 2), 256, 0, stream>>>(x, sigma, Hg, Wg);
    dct2net_k3<<<dim3(8, 488, 2), 64, 0, stream>>>(Hg, Wg, sigma, out);
}

// Round 11
// 173.572 us; speedup vs baseline: 1.0619x; 1.0112x over previous
//
#include <hip/hip_runtime.h>
#include <math.h>

// DCT2net, R16: R12 base + load-before-store vmcnt discipline + 1-step-delayed
// retire store + R13 wins (masked jj<13 store, 4-way pnz). Delay lines reverted.
//
// Cross-round evidence: inst/step varied 1.44x (R9 ~520 @85% busy, R15 ~360
// @68% busy) with wall time pinned 120-131us -> NOT VALU-issue bound. Theory:
// vmcnt retires in issue order; the scattered jj-plane Hg store (52 lines/wave)
// issued before the x prefetch load blocks the load's retirement -> every
// step's stage ds_write waits on store-ack latency. Fix: issue the prefetch
// load FIRST each step; delay the retire store one step (Hout/Wout staging) so
// it issues right after the load and drains with nothing waiting on it.
//
// Structure: per lane-group of 16 (13 kj used), one patch column; LDS-staged
// 16-wide x window (software-pipelined xq regs); sliding-DCT vertical
// recurrence (2 FMA/coeff, bootstrap 2 matvecs); scaled domain; DPP ROR16
// butterfly; register rings dr/wr/Hr; jj-plane Hg; single-wave k3.
//
// ws: Hg = 2*488*16*512 f32 (31.98 MB), Wg = 2*512*512 f32 (2 MB).

#define P13    13
#define IMGW   512
#define OUTW   488
#define SEGH   31      // 15*31 + 23 = 488
#define NSEG   16
#define HCOLS  512
#define HPITCH 16

struct C1mat { float v[P13 * P13]; };

// ---- compile-time DCT tables ----
constexpr double kPI = 3.14159265358979323846264338327950288;

constexpr double ccos_pm_pi(double th) {   // Taylor, |th| <= pi
    double term = 1.0, s = 1.0;
    const double th2 = th * th;
    for (int n = 1; n <= 25; ++n) {
        term *= -th2 / (double)((2 * n - 1) * (2 * n));
        s += term;
    }
    return s;
}
constexpr double csqrt(double v) {
    double x = (v > 1.0) ? v : 1.0;
    for (int i = 0; i < 64; ++i) x = 0.5 * (x + v / x);
    return x;
}
constexpr C1mat make_c1() {
    C1mat m{};
    const double s213 = csqrt(2.0 / 13.0);
    const double is2  = 1.0 / csqrt(2.0);
    for (int x = 0; x < P13; ++x)
        for (int k = 0; k < P13; ++k) {
            int mm = ((2 * x + 1) * k) % 52;
            double th = (mm <= 26) ? (mm * kPI / 26.0) : ((mm - 52) * kPI / 26.0);
            double Ci = (k == 0) ? is2 : 1.0;
            m.v[x * P13 + k] = (float)(s213 * Ci * ccos_pm_pi(th));
        }
    return m;
}
__device__ constexpr C1mat c1c = make_c1();

// c1[r][c] = sgn*A[idx]; A[q] = s213*cos(q*pi/26) (q=0..12), A[13] = s213/sqrt2.
// b[q] = 2*cos((q+1)*pi/13) (sliding-DCT recurrence constants).
struct CTab { int idx[P13][P13]; bool neg[P13][P13]; float a[14]; float b[6]; };
constexpr CTab make_ctab() {
    CTab t{};
    const double s213 = csqrt(2.0 / 13.0);
    for (int q = 0; q <= 12; ++q) t.a[q] = (float)(s213 * ccos_pm_pi(q * kPI / 26.0));
    t.a[13] = (float)(s213 / csqrt(2.0));
    for (int q = 0; q < 6; ++q) t.b[q] = (float)(2.0 * ccos_pm_pi((q + 1) * kPI / 13.0));
    for (int r = 0; r < P13; ++r)
        for (int c = 0; c < P13; ++c) {
            if (c == 0) { t.idx[r][c] = 13; t.neg[r][c] = false; continue; }
            int m = ((2 * r + 1) * c) % 52;
            int q; bool n;
            if (m <= 13)      { q = m;      n = false; }
            else if (m <= 26) { q = 26 - m; n = true;  }
            else if (m <= 39) { q = m - 26; n = true;  }
            else              { q = 52 - m; n = false; }
            t.idx[r][c] = q; t.neg[r][c] = n;
        }
    return t;
}
constexpr CTab ctab = make_ctab();

#define KC(r, c) (ctab.neg[(r)][(c)] ? -As[ctab.idx[(r)][(c)]] : As[ctab.idx[(r)][(c)]])

struct FalseT { static constexpr bool value = false; };
struct TrueT  { static constexpr bool value = true; };

// rotate-reduce add within each 16-lane DPP row: N in {1,2,4,8}
#define ROR16_ADD(v, N)                                                        \
    v += __int_as_float(__builtin_amdgcn_mov_dpp(__float_as_int(v),            \
                                                 0x120 + (N), 0xF, 0xF, true))

// weighted vertical inverse fold (scaled domain)
__device__ __forceinline__ void fold_vert(const float (&tn)[P13], const float (&As)[14],
                                          float w1, float (&H)[P13])
{
#pragma unroll
    for (int dx = 0; dx < 6; ++dx) {
        float E = KC(dx, 0) * tn[0];
#pragma unroll
        for (int i = 2; i < P13; i += 2) E = fmaf(KC(dx, i), tn[i], E);
        float O = KC(dx, 1) * tn[1];
#pragma unroll
        for (int i = 3; i < P13; i += 2) O = fmaf(KC(dx, i), tn[i], O);
        H[dx]      = fmaf(w1, E + O, H[dx]);
        H[12 - dx] = fmaf(w1, E - O, H[12 - dx]);
    }
    float z6 = KC(6, 0) * tn[0];
#pragma unroll
    for (int i = 2; i < P13; i += 2) z6 = fmaf(KC(6, i), tn[i], z6);
    H[6] = fmaf(w1, z6, H[6]);
}

__global__ __launch_bounds__(256) void dct2net_k2(
    const float* __restrict__ xg, const float* __restrict__ sigmag,
    float* __restrict__ Hg, float* __restrict__ Wg)
{
    __shared__ float c1lds[169];
    __shared__ float xlds[4][4][16];       // stride 16: 2 lanes/bank = free
    const int tid = threadIdx.x;
    if (tid < 169) c1lds[tid] = c1c.v[tid];
    __syncthreads();                       // once, for the c1 table only

    const int lane = tid & 63;
    const int wv   = tid >> 6;
    const int g    = lane >> 4;            // col group 0..3
    const int jj   = lane & 15;            // kj (0..12 used)
    const int img  = blockIdx.z;
    const int hs   = blockIdx.y * SEGH;
    const int segrows = (OUTW - hs < SEGH) ? (OUTW - hs) : SEGH;
    const int cbw  = blockIdx.x * 16 + wv * 4;
    const int col  = cbw + g;

    const float inv3s = 1.0f / (3.0f * sigmag[0]);
    const float* xin  = xg + (size_t)img * IMGW * IMGW;

    // SGPR constant pools
    float As[14], Bs[6];
#pragma unroll
    for (int q = 0; q < 14; ++q) As[q] = ctab.a[q];
#pragma unroll
    for (int q = 0; q < 6; ++q) Bs[q] = ctab.b[q];
#pragma unroll
    for (int q = 0; q < 14; ++q) asm("" : "+s"(As[q]));
#pragma unroll
    for (int q = 0; q < 6; ++q) asm("" : "+s"(Bs[q]));

    // per-lane window coefficients over staged positions p=0..15
    float c1x[16];
#pragma unroll
    for (int p = 0; p < 16; ++p) {
        int y = p - g;
        int yc = (y < 0) ? 0 : ((y > 12) ? 12 : y);
        int jc = (jj < 13) ? jj : 0;
        float v = c1lds[yc * 13 + jc];
        c1x[p] = (y >= 0 && y < 13 && jj < 13) ? v * inv3s : 0.0f;
    }

    float T0[P13], T1[P13], dr[P13], Hr[P13], wr[12], Rv[P13];
#pragma unroll
    for (int k = 0; k < P13; ++k) { T0[k]=0; T1[k]=0; dr[k]=0; Hr[k]=0; Rv[k]=0; }
#pragma unroll
    for (int k = 0; k < 12; ++k) wr[k] = 0.0f;
    float vs = 0.0f, Rprev = 0.0f;
    float Hout = 0.0f, Wout = 0.0f;        // 1-step store staging

    int xcol = cbw + (lane & 15); xcol = (xcol < IMGW - 1) ? xcol : (IMGW - 1);
    const float* xlast = xin + (size_t)(IMGW - 1) * IMGW;

    // ---- pre-roll: stage row hs, read window into xq, xvA <- row hs+1 ----
    float xq[16];
    float xvA, xvB;
    {
        const float* r0 = xin + (size_t)hs * IMGW;
        xlds[wv][g][jj] = r0[xcol];
        float4 q0 = *(const float4*)&xlds[wv][g][0];
        float4 q1 = *(const float4*)&xlds[wv][g][4];
        float4 q2 = *(const float4*)&xlds[wv][g][8];
        float4 q3 = *(const float4*)&xlds[wv][g][12];
        xq[0]=q0.x; xq[1]=q0.y; xq[2]=q0.z; xq[3]=q0.w;
        xq[4]=q1.x; xq[5]=q1.y; xq[6]=q1.z; xq[7]=q1.w;
        xq[8]=q2.x; xq[9]=q2.y; xq[10]=q2.z; xq[11]=q2.w;
        xq[12]=q3.x; xq[13]=q3.y; xq[14]=q3.z; xq[15]=q3.w;
        const float* r1 = xin + (size_t)(hs + 1) * IMGW;
        xvA = r1[xcol];
    }
    const float* xp = xin + (size_t)(hs + 2) * IMGW;

    float* Hp = Hg + ((size_t)img * OUTW + hs) * HPITCH * HCOLS;
    float* Wp = Wg + ((size_t)img * IMGW + hs) * IMGW;
    const int voH = jj * HCOLS + col;      // jj-plane layout
    const int voW = col;

    // issue next prefetch load FIRST in the step (older than any store)
    auto loadNext = [&](float& xvL) {
        const float* xr = (xp < xlast) ? xp : xlast;
        xvL = xr[xcol]; xp += IMGW;
    };
    // store of the PREVIOUS step's retired values (issued right after the load)
    auto storeOut = [&]() {
        if (jj < 13) Hp[voH] = Hout;       // planes 13..15 never read
        Hp += HPITCH * HCOLS;
        if (jj == 0) Wp[voW] = Wout;
        Wp += IMGW;
    };
    auto hdct = [&]() -> float {
        float a0 = c1x[0] * xq[0], a1 = c1x[1] * xq[1];
#pragma unroll
        for (int p = 2; p < 16; p += 2) a0 = fmaf(c1x[p], xq[p], a0);
#pragma unroll
        for (int p = 3; p < 16; p += 2) a1 = fmaf(c1x[p], xq[p], a1);
        return a0 + a1;
    };
    // stage next row (xvW) into LDS, refill xq window (end of step)
    auto stage = [&](float xvW) {
        xlds[wv][g][jj] = xvW;
        float4 q0 = *(const float4*)&xlds[wv][g][0];
        float4 q1 = *(const float4*)&xlds[wv][g][4];
        float4 q2 = *(const float4*)&xlds[wv][g][8];
        float4 q3 = *(const float4*)&xlds[wv][g][12];
        xq[0]=q0.x; xq[1]=q0.y; xq[2]=q0.z; xq[3]=q0.w;
        xq[4]=q1.x; xq[5]=q1.y; xq[6]=q1.z; xq[7]=q1.w;
        xq[8]=q2.x; xq[9]=q2.y; xq[10]=q2.z; xq[11]=q2.w;
        xq[12]=q3.x; xq[13]=q3.y; xq[14]=q3.z; xq[15]=q3.w;
    };
    auto pushRv = [&](float Rn) {
#pragma unroll
        for (int q = 0; q < P13 - 1; ++q) Rv[q] = Rv[q + 1];
        Rv[P13 - 1] = Rn;
    };
    auto pushd = [&](float Rn) {
        float dn = Rn - Rprev; Rprev = Rn;
#pragma unroll
        for (int q = 0; q < P13 - 1; ++q) dr[q] = dr[q + 1];
        dr[P13 - 1] = dn;
    };
    auto matvec = [&](float (&T)[P13]) {   // bootstrap only
        float Se[6], So[6];
#pragma unroll
        for (int k = 0; k < 6; ++k) { Se[k] = Rv[k] + Rv[12 - k]; So[k] = Rv[k] - Rv[12 - k]; }
#pragma unroll
        for (int i = 0; i < P13; ++i) {
            float t;
            if ((i & 1) == 0) {
                t = KC(6, i) * Rv[6];
#pragma unroll
                for (int k = 0; k < 6; ++k) t = fmaf(KC(k, i), Se[k], t);
            } else {
                t = KC(0, i) * So[0];
#pragma unroll
                for (int k = 1; k < 6; ++k) t = fmaf(KC(k, i), So[k], t);
            }
            T[i] = t;
        }
    };
    // shrink + butterfly + fold + (runtime) retire-to-staging. T pre-scaled.
    auto sf = [&](const float (&T)[P13], bool retireNow) {
        float tn[P13];
        float pz0 = 0.0f, pz1 = 0.0f, pz2 = 0.0f, pz3 = 0.0f;
#pragma unroll
        for (int i = 0; i < P13; ++i) {
            float p2 = fminf(T[i] * T[i], 1.69f);
            float p4 = p2 * p2, p8 = p4 * p4, p16 = p8 * p8, p32 = p16 * p16, p64 = p32 * p32;
            float r  = __builtin_amdgcn_rcpf(p64 + 1.0f);
            if ((i & 3) == 0) pz0 += r;
            else if ((i & 3) == 1) pz1 += r;
            else if ((i & 3) == 2) pz2 += r;
            else pz3 += r;
            tn[i] = fmaf(-T[i], r, T[i]);
        }
        float pnz = 13.0f - ((pz0 + pz1) + (pz2 + pz3));   // idle lanes: 0
        ROR16_ADD(pnz, 1); ROR16_ADD(pnz, 2); ROR16_ADD(pnz, 4); ROR16_ADD(pnz, 8);
        const float w = __builtin_amdgcn_rcpf(1.0f + pnz);
        vs += w;
        fold_vert(tn, As, w, Hr);
        if (retireNow) {                    // stage for next step's store
            Hout = Hr[0];
            Wout = vs;
            vs  -= wr[0];
        }
#pragma unroll
        for (int q = 0; q < 11; ++q) wr[q] = wr[q + 1];
        wr[11] = w;
#pragma unroll
        for (int q = 0; q < P13 - 1; ++q) Hr[q] = Hr[q + 1];
        Hr[P13 - 1] = 0.0f;
    };
    auto recur = [&](auto INTOT0, float& xvW, float& xvL, bool storePrev, bool retireNow) {
        loadNext(xvL);                      // oldest vmem op of the step
        if (storePrev) storeOut();          // scattered store: full step to drain
        float Rn = hdct();
        float dn = Rn - Rprev; Rprev = Rn;
        float dl = dr[0];
#pragma unroll
        for (int q = 0; q < P13 - 1; ++q) dr[q] = dr[q + 1];
        dr[P13 - 1] = dn;
        float Pe = dn - dl, Po = dn + dl;
#pragma unroll
        for (int i = 0; i < P13; ++i) {
            float tp2 = decltype(INTOT0)::value ? T0[i] : T1[i];
            float tp1 = decltype(INTOT0)::value ? T1[i] : T0[i];
            float c2 = (i == 0) ? 2.0f : ((i <= 6) ? Bs[i - 1] : -Bs[12 - i]);
            float t = fmaf(c2, tp1, -tp2);
            float kc = (i == 0) ? As[13] : As[i];
            t = (i & 1) ? fmaf(-kc, Po, t) : fmaf(kc, Pe, t);
            if constexpr (decltype(INTOT0)::value) T0[i] = t; else T1[i] = t;
        }
        if constexpr (decltype(INTOT0)::value) sf(T0, retireNow); else sf(T1, retireNow);
        stage(xvW);                         // end of step: LDS refill
    };

    // ---- ramp1: k=0..11 (load first, stage last; no stores yet) ----
    { loadNext(xvB); float Rn = hdct(); Rprev = Rn; pushRv(Rn); stage(xvA); }
    { loadNext(xvA); float Rn = hdct(); pushd(Rn); pushRv(Rn); stage(xvB); }
#pragma unroll 1
    for (int k = 2; k < 12; k += 2) {
        { loadNext(xvB); float Rn = hdct(); pushd(Rn); pushRv(Rn); stage(xvA); }
        { loadNext(xvA); float Rn = hdct(); pushd(Rn); pushRv(Rn); stage(xvB); }
    }
    // ---- bootstrap: direct matvecs at k=12 (T0), k=13 (T1) ----
    { loadNext(xvB); float Rn = hdct(); pushd(Rn); pushRv(Rn);
      matvec(T0); sf(T0, false); stage(xvA); }
    { loadNext(xvA); float Rn = hdct(); pushd(Rn); pushRv(Rn);
      matvec(T1); sf(T1, false); stage(xvB); }
    // ---- steady: retire from step 10; store lags retire by one step ----
    {
        int ks = 0; const int S = 10 + segrows;
#pragma unroll 1
        while (ks + 2 <= S) {
            recur(TrueT{},  xvA, xvB, ks     >= 11, ks     >= 10);
            recur(FalseT{}, xvB, xvA, ks + 1 >= 11, ks + 1 >= 10);
            ks += 2;
        }
        if (ks < S) recur(TrueT{}, xvA, xvB, ks >= 11, ks >= 10);
        storeOut();                         // flush last staged retire
    }
}

__global__ __launch_bounds__(64) void dct2net_k3(
    const float* __restrict__ Hg, const float* __restrict__ Wg,
    const float* __restrict__ sigmag, float* __restrict__ outg)
{
    __shared__ float U[76][15];      // stride 15: diag read 2-way alias (free)
    __shared__ float vw[80];
    const int lane = threadIdx.x;    // single wave per block
    const int img  = blockIdx.z;
    const int a    = blockIdx.y;     // out row 0..487
    const int cb   = blockIdx.x * 64;

    const float t3s = 3.0f * sigmag[0];     // undo k2's scaled domain

    float As[14];
#pragma unroll
    for (int q = 0; q < 14; ++q) As[q] = ctab.a[q];
#pragma unroll
    for (int q = 0; q < 14; ++q) asm("" : "+s"(As[q]));

    // ---- coalesced loads from jj-plane Hg (main + halo issued up front) ----
    int c = cb + lane; c = (c < 499) ? c : 499;
    const float* hb = Hg + ((size_t)img * OUTW + a) * HPITCH * HCOLS + c;
    float hv[P13];
#pragma unroll
    for (int j = 0; j < P13; ++j) hv[j] = hb[j * HCOLS];
    float wm = Wg[((size_t)img * IMGW + a) * IMGW + c];

    const bool halo = (lane < 12);
    float sv[P13]; float ws = 0.0f;
#pragma unroll
    for (int j = 0; j < P13; ++j) sv[j] = 0.0f;
    if (halo) {
        int c2 = cb + 64 + lane; c2 = (c2 < 499) ? c2 : 499;
        const float* hq = Hg + ((size_t)img * OUTW + a) * HPITCH * HCOLS + c2;
#pragma unroll
        for (int j = 0; j < P13; ++j) sv[j] = hq[j * HCOLS];
        ws = Wg[((size_t)img * IMGW + a) * IMGW + c2];
    }

    // U build with row symmetry: c1[12-dy][j] = (-1)^j c1[dy][j]
    auto buildU = [&](const float (&h)[P13], int uli) {
#pragma unroll
        for (int dy = 0; dy < 6; ++dy) {
            float e = KC(dy, 0) * h[0];
#pragma unroll
            for (int j = 2; j < P13; j += 2) e = fmaf(KC(dy, j), h[j], e);
            float o = KC(dy, 1) * h[1];
#pragma unroll
            for (int j = 3; j < P13; j += 2) o = fmaf(KC(dy, j), h[j], o);
            U[uli][dy]      = e + o;
            U[uli][12 - dy] = e - o;
        }
        float gsum = ((h[4] - h[2]) + (h[8] - h[6])) + (h[12] - h[10]);
        U[uli][6] = fmaf(As[0], gsum, As[13] * h[0]);
    };

    buildU(hv, lane);
    vw[lane] = wm;
    if (halo) {
        buildU(sv, 64 + lane);
        vw[64 + lane] = ws;
    }
    // single wave: LDS write->read in program order, no barrier

    float num = 0.0f;
#pragma unroll
    for (int dy = 0; dy < P13; ++dy) num += U[lane + 12 - dy][dy];
    float den = 0.0f;
#pragma unroll
    for (int d = 0; d < P13; ++d) den += vw[lane + d];
    const int ow = cb + lane;
    if (ow < OUTW)
        outg[((size_t)img * OUTW + a) * OUTW + ow] =
            num * t3s * __builtin_amdgcn_rcpf(den);
}

extern "C" void kernel_launch(void* const* d_in, const int* in_sizes, int n_in,
                              void* d_out, int out_size, void* d_ws, size_t ws_size,
                              hipStream_t stream)
{
    const float* x     = (const float*)d_in[0];
    const float* sigma = (const float*)d_in[1];
    float* out = (float*)d_out;

    // ws: Hg (2*488*16*512 f32 = 31.98 MB) then Wg (2*512*512 f32 = 2 MB)
    float* Hg = (float*)d_ws;
    float* Wg = Hg + (size_t)2 * OUTW * HPITCH * HCOLS;

    dct2net_k2<<<dim3(32, NSEG, 2), 256, 0, stream>>>(x, sigma, Hg, Wg);
    dct2net_k3<<<dim3(8, 488, 2), 64, 0, stream>>>(Hg, Wg, sigma, out);
}